// Round 1
// baseline (636.731 us; speedup 1.0000x reference)
//
#include <hip/hip_runtime.h>
#include <stdint.h>

#define TT 4
#define BB 8
#define CC 512
#define NN 1024
#define HH 8

typedef unsigned char u8;

// Fused: Y = W @ X per (t,b)  ->  BN  ->  LIF over t  ->  binary spikes (u8)
// grid (CC/64, NN/64, BB), block 256
__global__ __launch_bounds__(256)
void k_gemm_bn_lif(const float* __restrict__ X, const float* __restrict__ W,
                   const float* __restrict__ gamma, const float* __restrict__ beta,
                   const float* __restrict__ mean, const float* __restrict__ var,
                   u8* __restrict__ S)
{
    const int d0 = blockIdx.x << 6;
    const int n0 = blockIdx.y << 6;
    const int b  = blockIdx.z;
    const int tid = threadIdx.x;
    const int tx = tid & 15;   // n direction
    const int ty = tid >> 4;   // d direction

    __shared__ float Ws[16][68];       // [k][m], +4 pad: conflict-free, 16B-aligned rows
    __shared__ float Xs[4][16][64];    // [t][k][n]

    float acc[4][4][4];
#pragma unroll
    for (int t = 0; t < 4; ++t)
#pragma unroll
        for (int i = 0; i < 4; ++i)
#pragma unroll
            for (int j = 0; j < 4; ++j) acc[t][i][j] = 0.0f;

    const int wk = tid & 15;             // k for W staging (coalesced along c)
    const int wm = (tid >> 4) << 2;      // m base
    const int xj = tid & 63;             // n for X staging (coalesced)
    const int xr = tid >> 6;             // row base 0..3

    for (int kt = 0; kt < CC; kt += 16) {
#pragma unroll
        for (int r = 0; r < 4; ++r)
            Ws[wk][wm + r] = W[(size_t)(d0 + wm + r) * CC + kt + wk];
#pragma unroll
        for (int t = 0; t < 4; ++t) {
            const float* xp = X + ((size_t)(t * BB + b) * CC + kt) * NN + n0;
#pragma unroll
            for (int r = 0; r < 4; ++r) {
                const int row = xr + (r << 2);
                Xs[t][row][xj] = xp[(size_t)row * NN + xj];
            }
        }
        __syncthreads();
#pragma unroll
        for (int kk = 0; kk < 16; ++kk) {
            float w[4], x[4];
            *(float4*)w = *(const float4*)&Ws[kk][ty << 2];
#pragma unroll
            for (int t = 0; t < 4; ++t) {
                *(float4*)x = *(const float4*)&Xs[t][kk][tx << 2];
#pragma unroll
                for (int i = 0; i < 4; ++i)
#pragma unroll
                    for (int j = 0; j < 4; ++j)
                        acc[t][i][j] = fmaf(w[i], x[j], acc[t][i][j]);
            }
        }
        __syncthreads();
    }

    const int dbase = d0 + (ty << 2);
    const int nbase = n0 + (tx << 2);
#pragma unroll
    for (int i = 0; i < 4; ++i) {
        const int d = dbase + i;
        const float inv = gamma[d] * (1.0f / sqrtf(var[d] + 1e-5f));
        const float mu = mean[d];
        const float be = beta[d];
        float v0 = 0.f, v1 = 0.f, v2 = 0.f, v3 = 0.f;
#pragma unroll
        for (int t = 0; t < 4; ++t) {
            const float y0 = (acc[t][i][0] - mu) * inv + be;
            const float y1 = (acc[t][i][1] - mu) * inv + be;
            const float y2 = (acc[t][i][2] - mu) * inv + be;
            const float y3 = (acc[t][i][3] - mu) * inv + be;
            v0 += (y0 - v0) * 0.5f; v1 += (y1 - v1) * 0.5f;
            v2 += (y2 - v2) * 0.5f; v3 += (y3 - v3) * 0.5f;
            const u8 s0 = v0 >= 1.0f, s1 = v1 >= 1.0f, s2 = v2 >= 1.0f, s3 = v3 >= 1.0f;
            if (s0) v0 = 0.f; if (s1) v1 = 0.f; if (s2) v2 = 0.f; if (s3) v3 = 0.f;
            *(uchar4*)&S[((size_t)(t * BB + b) * CC + d) * NN + nbase] =
                make_uchar4(s0, s1, s2, s3);
        }
    }
}

// attn[t,b,h,n] = (sum_d q_s[t,b,h*64+d,n] >= 1)  == byte-wise OR (exact)
// grid (1, HH, TT*BB), block 256; each thread handles 4 n via u32 OR
__global__ __launch_bounds__(256)
void k_attn(const u8* __restrict__ Sq, u8* __restrict__ A)
{
    const int n4 = threadIdx.x;
    const int h  = blockIdx.y;
    const int tb = blockIdx.z;
    const u8* p = Sq + ((size_t)tb * CC + (h << 6)) * NN + (n4 << 2);
    uint32_t acc = 0;
#pragma unroll 8
    for (int d = 0; d < 64; ++d)
        acc |= *(const uint32_t*)(p + (size_t)d * NN);
    *(uint32_t*)(A + ((size_t)tb * HH + h) * NN + (n4 << 2)) = acc;
}

// proj: x = attn & k_s (formed during staging) -> GEMM + bias + BN + LIF -> fp32 spikes
__global__ __launch_bounds__(256)
void k_proj(const u8* __restrict__ Sk, const u8* __restrict__ A,
            const float* __restrict__ W, const float* __restrict__ bias,
            const float* __restrict__ gamma, const float* __restrict__ beta,
            const float* __restrict__ mean, const float* __restrict__ var,
            float* __restrict__ O)
{
    const int d0 = blockIdx.x << 6;
    const int n0 = blockIdx.y << 6;
    const int b  = blockIdx.z;
    const int tid = threadIdx.x;
    const int tx = tid & 15;
    const int ty = tid >> 4;

    __shared__ float Ws[16][68];
    __shared__ float Xs[4][16][64];

    float acc[4][4][4];
#pragma unroll
    for (int t = 0; t < 4; ++t)
#pragma unroll
        for (int i = 0; i < 4; ++i)
#pragma unroll
            for (int j = 0; j < 4; ++j) acc[t][i][j] = 0.0f;

    const int wk = tid & 15;
    const int wm = (tid >> 4) << 2;
    const int xj = tid & 63;
    const int xr = tid >> 6;

    for (int kt = 0; kt < CC; kt += 16) {
#pragma unroll
        for (int r = 0; r < 4; ++r)
            Ws[wk][wm + r] = W[(size_t)(d0 + wm + r) * CC + kt + wk];
#pragma unroll
        for (int t = 0; t < 4; ++t) {
            const size_t tbC = (size_t)(t * BB + b) * CC;
            const u8* ap = A + (size_t)(t * BB + b) * HH * NN + n0;
#pragma unroll
            for (int r = 0; r < 4; ++r) {
                const int row = xr + (r << 2);
                const int c = kt + row;
                const u8 ks = Sk[(tbC + c) * NN + n0 + xj];
                const u8 at = ap[(size_t)(c >> 6) * NN + xj];
                Xs[t][row][xj] = (float)(ks & at);
            }
        }
        __syncthreads();
#pragma unroll
        for (int kk = 0; kk < 16; ++kk) {
            float w[4], x[4];
            *(float4*)w = *(const float4*)&Ws[kk][ty << 2];
#pragma unroll
            for (int t = 0; t < 4; ++t) {
                *(float4*)x = *(const float4*)&Xs[t][kk][tx << 2];
#pragma unroll
                for (int i = 0; i < 4; ++i)
#pragma unroll
                    for (int j = 0; j < 4; ++j)
                        acc[t][i][j] = fmaf(w[i], x[j], acc[t][i][j]);
            }
        }
        __syncthreads();
    }

    const int dbase = d0 + (ty << 2);
    const int nbase = n0 + (tx << 2);
#pragma unroll
    for (int i = 0; i < 4; ++i) {
        const int d = dbase + i;
        const float bs = bias[d];
        const float inv = gamma[d] * (1.0f / sqrtf(var[d] + 1e-5f));
        const float mu = mean[d];
        const float be = beta[d];
        float v0 = 0.f, v1 = 0.f, v2 = 0.f, v3 = 0.f;
#pragma unroll
        for (int t = 0; t < 4; ++t) {
            const float y0 = ((acc[t][i][0] + bs) - mu) * inv + be;
            const float y1 = ((acc[t][i][1] + bs) - mu) * inv + be;
            const float y2 = ((acc[t][i][2] + bs) - mu) * inv + be;
            const float y3 = ((acc[t][i][3] + bs) - mu) * inv + be;
            v0 += (y0 - v0) * 0.5f; v1 += (y1 - v1) * 0.5f;
            v2 += (y2 - v2) * 0.5f; v3 += (y3 - v3) * 0.5f;
            const bool s0 = v0 >= 1.0f, s1 = v1 >= 1.0f, s2 = v2 >= 1.0f, s3 = v3 >= 1.0f;
            if (s0) v0 = 0.f; if (s1) v1 = 0.f; if (s2) v2 = 0.f; if (s3) v3 = 0.f;
            *(float4*)&O[((size_t)(t * BB + b) * CC + d) * NN + nbase] =
                make_float4(s0 ? 1.f : 0.f, s1 ? 1.f : 0.f, s2 ? 1.f : 0.f, s3 ? 1.f : 0.f);
        }
    }
}

extern "C" void kernel_launch(void* const* d_in, const int* in_sizes, int n_in,
                              void* d_out, int out_size, void* d_ws, size_t ws_size,
                              hipStream_t stream)
{
    const float* q   = (const float*)d_in[0];
    const float* k   = (const float*)d_in[1];
    const float* qw  = (const float*)d_in[2];
    const float* kw  = (const float*)d_in[3];
    const float* pw  = (const float*)d_in[4];
    const float* pb  = (const float*)d_in[5];
    const float* qg  = (const float*)d_in[6];
    const float* qbt = (const float*)d_in[7];
    const float* qm  = (const float*)d_in[8];
    const float* qv  = (const float*)d_in[9];
    const float* kg  = (const float*)d_in[10];
    const float* kbt = (const float*)d_in[11];
    const float* km  = (const float*)d_in[12];
    const float* kv  = (const float*)d_in[13];
    const float* pg  = (const float*)d_in[14];
    const float* pbt = (const float*)d_in[15];
    const float* pm  = (const float*)d_in[16];
    const float* pv  = (const float*)d_in[17];

    u8* Sq = (u8*)d_ws;
    u8* Sk = Sq + (size_t)TT * BB * CC * NN;
    u8* Aa = Sk + (size_t)TT * BB * CC * NN;

    dim3 blk(256);
    dim3 g1(CC / 64, NN / 64, BB);
    k_gemm_bn_lif<<<g1, blk, 0, stream>>>(q, qw, qg, qbt, qm, qv, Sq);
    k_gemm_bn_lif<<<g1, blk, 0, stream>>>(k, kw, kg, kbt, km, kv, Sk);
    k_attn<<<dim3(1, HH, TT * BB), blk, 0, stream>>>(Sq, Aa);
    k_proj<<<g1, blk, 0, stream>>>(Sk, Aa, pw, pb, pg, pbt, pm, pv, (float*)d_out);
}

// Round 2
// 324.875 us; speedup vs baseline: 1.9599x; 1.9599x over previous
//
#include <hip/hip_runtime.h>
#include <stdint.h>

#define TT 4
#define BB 8
#define CC 512
#define NN 1024
#define HH 8

typedef unsigned char u8;
typedef short bf16x8 __attribute__((ext_vector_type(8)));
typedef float f32x16 __attribute__((ext_vector_type(16)));

#define WF_BYTES (3u*64u*512u*16u)            /* 1,572,864 per weight */
#define SZ_SPIKE ((size_t)TT*BB*CC*NN)        /* 16 MiB */

union U4B { uint4 u; bf16x8 v; };
__device__ __forceinline__ bf16x8 asbf(uint4 u){ U4B x; x.u = u; return x.v; }

__device__ __forceinline__ uint32_t rne_hi(uint32_t u){
  return (u + 0x7FFFu + ((u >> 16) & 1u)) & 0xFFFF0000u;   // RNE to bf16, kept in fp32-bit position
}
__device__ __forceinline__ uint32_t pk2(uint32_t hi, uint32_t lo){
  return __builtin_amdgcn_perm(hi, lo, 0x07060302u);       // (hi16(hi)<<16)|hi16(lo)
}
// exact 3-way bf16 split of 8 fp32 (x == h+m+l exactly; RNE,RNE,trunc)
__device__ __forceinline__ void split8(const float* x, uint32_t* H, uint32_t* M, uint32_t* L){
  uint32_t hb[8], mb[8], lb[8];
#pragma unroll
  for (int e = 0; e < 8; ++e){
    uint32_t u = __float_as_uint(x[e]);
    hb[e] = rne_hi(u);
    float r1 = x[e] - __uint_as_float(hb[e]);
    uint32_t u1 = __float_as_uint(r1);
    mb[e] = rne_hi(u1);
    float r2 = r1 - __uint_as_float(mb[e]);
    lb[e] = __float_as_uint(r2) & 0xFFFF0000u;
  }
#pragma unroll
  for (int p = 0; p < 4; ++p){
    H[p] = pk2(hb[2*p+1], hb[2*p]);
    M[p] = pk2(mb[2*p+1], mb[2*p]);
    L[p] = pk2(lb[2*p+1], lb[2*p]);
  }
}

__device__ __forceinline__ void gld_lds16(const void* g, void* l){
  __builtin_amdgcn_global_load_lds((const __attribute__((address_space(1))) void*)g,
                                   (__attribute__((address_space(3))) void*)l, 16, 0, 0);
}
__device__ __forceinline__ void gld_lds4(const void* g, void* l){
  __builtin_amdgcn_global_load_lds((const __attribute__((address_space(1))) void*)g,
                                   (__attribute__((address_space(3))) void*)l, 4, 0, 0);
}

#define MFMA_B16(a,b,c) __builtin_amdgcn_mfma_f32_32x32x16_bf16((a),(b),(c),0,0,0)

// ---------------------------------------------------------------------------
// prep: W [512x512] fp32 -> 3-level bf16 fragments, layout [s][kh 64][row 512]
// frag16B(s,kh,row) holds k = kh*8 + e for row d.  grid (128,3) x 256
// ---------------------------------------------------------------------------
__global__ __launch_bounds__(256)
void k_prep(const float* __restrict__ W0, const float* __restrict__ W1,
            const float* __restrict__ W2,
            u8* __restrict__ D0, u8* __restrict__ D1, u8* __restrict__ D2)
{
  const int which = blockIdx.y;
  const float* W = (which == 0) ? W0 : (which == 1) ? W1 : W2;
  u8* D = (which == 0) ? D0 : (which == 1) ? D1 : D2;
  const int tg  = blockIdx.x * 256 + threadIdx.x;  // 0..32767
  const int row = tg >> 6;
  const int kh  = tg & 63;
  float x[8];
#pragma unroll
  for (int e = 0; e < 8; ++e) x[e] = W[row * CC + kh * 8 + e];
  uint32_t H[4], M[4], L[4];
  split8(x, H, M, L);
  *(uint4*)(D + ((size_t)((0*64 + kh)*512 + row)) * 16) = make_uint4(H[0],H[1],H[2],H[3]);
  *(uint4*)(D + ((size_t)((1*64 + kh)*512 + row)) * 16) = make_uint4(M[0],M[1],M[2],M[3]);
  *(uint4*)(D + ((size_t)((2*64 + kh)*512 + row)) * 16) = make_uint4(L[0],L[1],L[2],L[3]);
}

// ---------------------------------------------------------------------------
// q/k path: fp32-exact GEMM via bf16x3 (6 passes) + BN + LIF -> u8 spikes
// block 256 thr (4 waves, 2x2 of 64x64 tiles); tile: 128 d x (4t x 32 n)
// grid (4 dtiles, 32 ntiles, 8 b)   [dtile fastest for L2 reuse of X]
// ---------------------------------------------------------------------------
union LdsQK {
  struct { float xf[TT*64*32]; uint4 frag[3*8*128]; } s;   // 32 KiB + 48 KiB
  float y[128*129];                                        // 64.5 KiB
};

__global__ __launch_bounds__(256, 2)
void k_qk(const float* __restrict__ X, const u8* __restrict__ WF,
          const float* __restrict__ gamma, const float* __restrict__ beta,
          const float* __restrict__ mean, const float* __restrict__ var,
          u8* __restrict__ S)
{
  __shared__ LdsQK Lds;
  const int d0 = blockIdx.x << 7;
  const int n0 = blockIdx.y << 5;
  const int b  = blockIdx.z;
  const int tid  = threadIdx.x;
  const int lane = tid & 63;
  const int wid  = tid >> 6;
  const int wr = wid >> 1, wc = wid & 1;

  f32x16 acc[2][2];
#pragma unroll
  for (int i = 0; i < 2; ++i)
#pragma unroll
    for (int j = 0; j < 2; ++j)
#pragma unroll
      for (int r = 0; r < 16; ++r) acc[i][j][r] = 0.0f;

  // wave 'wid' stages t = wid rows of X tile into LDS (linear dest)
  auto stage1 = [&](int kt){
    const float* xb = X + ((size_t)(wid*BB + b)*CC + kt)*NN + n0 + ((lane & 7) << 2);
#pragma unroll
    for (int i = 0; i < 8; ++i){
      const float* g = xb + (size_t)(i*8 + (lane >> 3)) * NN;
      gld_lds16(g, (void*)&Lds.s.xf[(wid*64 + i*8) * 32]);
    }
  };

  stage1(0);

  for (int kti = 0; kti < 8; ++kti){
    const int kt = kti * 64;
    asm volatile("s_waitcnt vmcnt(0)" ::: "memory");
    __syncthreads();

    { // stage2: split fp32 -> 3x bf16 frags (pre-fragmented, linear slots)
      const int col = tid & 127;      // col = t*32 + n
      const int grp = tid >> 7;
      const int t = col >> 5, n = col & 31;
#pragma unroll
      for (int j = 0; j < 4; ++j){
        const int kh = grp*4 + j;
        float x[8];
#pragma unroll
        for (int e = 0; e < 8; ++e) x[e] = Lds.s.xf[(t*64 + kh*8 + e)*32 + n];
        uint32_t H[4], M[4], L[4];
        split8(x, H, M, L);
        Lds.s.frag[(0*8 + kh)*128 + col] = make_uint4(H[0],H[1],H[2],H[3]);
        Lds.s.frag[(1*8 + kh)*128 + col] = make_uint4(M[0],M[1],M[2],M[3]);
        Lds.s.frag[(2*8 + kh)*128 + col] = make_uint4(L[0],L[1],L[2],L[3]);
      }
    }
    __syncthreads();
    if (kti < 7) stage1(kt + 64);     // overlaps MFMA phase

    // A fragments for this K-tile (from prepped W, L2-resident)
    uint4 A[3][2][4];                 // [w-split][rt][ks]
#pragma unroll
    for (int s = 0; s < 3; ++s)
#pragma unroll
      for (int ks = 0; ks < 4; ++ks)
#pragma unroll
        for (int rt = 0; rt < 2; ++rt){
          const size_t idx = (size_t)(s*64 + (kti*4 + ks)*2 + (lane >> 5))*512
                           + d0 + wr*64 + rt*32 + (lane & 31);
          A[s][rt][ks] = *(const uint4*)(WF + idx * 16);
        }

#pragma unroll
    for (int ks = 0; ks < 4; ++ks){
#pragma unroll
      for (int ct = 0; ct < 2; ++ct){
        const int fb = wc*64 + ct*32 + (lane & 31);
        const int kb = ks*2 + (lane >> 5);
        bf16x8 bh = asbf(Lds.s.frag[(0*8 + kb)*128 + fb]);
        bf16x8 bm = asbf(Lds.s.frag[(1*8 + kb)*128 + fb]);
        bf16x8 bl = asbf(Lds.s.frag[(2*8 + kb)*128 + fb]);
        acc[0][ct] = MFMA_B16(asbf(A[0][0][ks]), bh, acc[0][ct]);
        acc[1][ct] = MFMA_B16(asbf(A[0][1][ks]), bh, acc[1][ct]);
        acc[0][ct] = MFMA_B16(asbf(A[1][0][ks]), bh, acc[0][ct]);
        acc[1][ct] = MFMA_B16(asbf(A[1][1][ks]), bh, acc[1][ct]);
        acc[0][ct] = MFMA_B16(asbf(A[2][0][ks]), bh, acc[0][ct]);
        acc[1][ct] = MFMA_B16(asbf(A[2][1][ks]), bh, acc[1][ct]);
        acc[0][ct] = MFMA_B16(asbf(A[0][0][ks]), bm, acc[0][ct]);
        acc[1][ct] = MFMA_B16(asbf(A[0][1][ks]), bm, acc[1][ct]);
        acc[0][ct] = MFMA_B16(asbf(A[1][0][ks]), bm, acc[0][ct]);
        acc[1][ct] = MFMA_B16(asbf(A[1][1][ks]), bm, acc[1][ct]);
        acc[0][ct] = MFMA_B16(asbf(A[0][0][ks]), bl, acc[0][ct]);
        acc[1][ct] = MFMA_B16(asbf(A[0][1][ks]), bl, acc[1][ct]);
      }
    }
  }

  __syncthreads();   // frags dead; reuse LDS as y tile
#pragma unroll
  for (int rt = 0; rt < 2; ++rt)
#pragma unroll
    for (int ct = 0; ct < 2; ++ct)
#pragma unroll
      for (int r = 0; r < 16; ++r){
        const int row = wr*64 + rt*32 + (r & 3) + ((r >> 2) << 3) + ((lane >> 5) << 2);
        const int col = wc*64 + ct*32 + (lane & 31);
        Lds.y[row*129 + col] = acc[rt][ct][r];
      }
  __syncthreads();

  const int d = tid & 127, nh = tid >> 7;
  const int dg = d0 + d;
  const float inv = gamma[dg] * (1.0f / sqrtf(var[dg] + 1e-5f));
  const float mu = mean[dg], be = beta[dg];
  uint32_t pk[TT][4] = {{0,0,0,0},{0,0,0,0},{0,0,0,0},{0,0,0,0}};
#pragma unroll
  for (int j = 0; j < 16; ++j){
    float v = 0.f;
#pragma unroll
    for (int t = 0; t < TT; ++t){
      float y = Lds.y[d*129 + t*32 + nh*16 + j];
      y = (y - mu) * inv + be;
      v += (y - v) * 0.5f;
      uint32_t s = (v >= 1.0f) ? 1u : 0u;
      if (s) v = 0.f;
      pk[t][j >> 2] |= s << ((j & 3) * 8);
    }
  }
#pragma unroll
  for (int t = 0; t < TT; ++t)
    *(uint4*)&S[((size_t)(t*BB + b)*CC + dg)*NN + n0 + nh*16] =
        make_uint4(pk[t][0], pk[t][1], pk[t][2], pk[t][3]);
}

// ---------------------------------------------------------------------------
// attn gate: byte-OR over the 64 channels of each head (exact LIF equivalent)
// ---------------------------------------------------------------------------
__global__ __launch_bounds__(256)
void k_attn(const u8* __restrict__ Sq, u8* __restrict__ A)
{
  const int n4 = threadIdx.x;
  const int h  = blockIdx.y;
  const int tb = blockIdx.z;
  const u8* p = Sq + ((size_t)tb * CC + (h << 6)) * NN + (n4 << 2);
  uint32_t acc = 0;
#pragma unroll 8
  for (int d = 0; d < 64; ++d)
    acc |= *(const uint32_t*)(p + (size_t)d * NN);
  *(uint32_t*)(A + ((size_t)tb * HH + h) * NN + (n4 << 2)) = acc;
}

// ---------------------------------------------------------------------------
// proj: x = (attn & k_s) exact in bf16; W 3-level split -> 3 passes; +bias,BN,LIF
// same geometry as k_qk
// ---------------------------------------------------------------------------
union LdsPJ {
  struct { u8 xu[TT*64*32]; uint4 frag[8*128]; } s;  // 8 KiB + 16 KiB
  float y[128*129];
};

__global__ __launch_bounds__(256, 2)
void k_proj(const u8* __restrict__ Sk, const u8* __restrict__ Ag,
            const u8* __restrict__ WF, const float* __restrict__ bias,
            const float* __restrict__ gamma, const float* __restrict__ beta,
            const float* __restrict__ mean, const float* __restrict__ var,
            float* __restrict__ O)
{
  __shared__ LdsPJ Lds;
  const int d0 = blockIdx.x << 7;
  const int n0 = blockIdx.y << 5;
  const int b  = blockIdx.z;
  const int tid  = threadIdx.x;
  const int lane = tid & 63;
  const int wid  = tid >> 6;
  const int wr = wid >> 1, wc = wid & 1;

  f32x16 acc[2][2];
#pragma unroll
  for (int i = 0; i < 2; ++i)
#pragma unroll
    for (int j = 0; j < 2; ++j)
#pragma unroll
      for (int r = 0; r < 16; ++r) acc[i][j][r] = 0.0f;

  auto stage1 = [&](int kt){
    const u8* xb = Sk + ((size_t)(wid*BB + b)*CC + kt)*NN + n0 + ((lane & 7) << 2);
#pragma unroll
    for (int i = 0; i < 8; ++i){
      const u8* g = xb + (size_t)(i*8 + (lane >> 3)) * NN;
      gld_lds4(g, (void*)&Lds.s.xu[(wid*64 + i*8) * 32]);
    }
  };

  stage1(0);

  for (int kti = 0; kti < 8; ++kti){
    const int kt = kti * 64;
    asm volatile("s_waitcnt vmcnt(0)" ::: "memory");
    __syncthreads();

    { // stage2: 8c x 4n byte transpose (v_perm) + gate + u8 -> bf16 {0,1}
      const int kh = tid >> 5;          // 0..7
      const int t  = (tid >> 3) & 3;
      const int n4 = tid & 7;
      uint32_t g32 = *(const uint32_t*)(Ag + ((size_t)(t*BB + b)*HH + kti)*NN + n0 + n4*4);
      uint32_t r[8];
#pragma unroll
      for (int c = 0; c < 8; ++c)
        r[c] = *(const uint32_t*)&Lds.s.xu[(t*64 + kh*8 + c)*32 + n4*4];
#pragma unroll
      for (int j = 0; j < 4; ++j){
        const uint32_t gm   = __builtin_amdgcn_perm(g32, g32, (uint32_t)j * 0x01010101u);
        const uint32_t selp = (uint32_t)j | (((uint32_t)j + 4u) << 8);
        uint32_t p01 = __builtin_amdgcn_perm(r[1], r[0], selp);
        uint32_t p23 = __builtin_amdgcn_perm(r[3], r[2], selp);
        uint32_t p45 = __builtin_amdgcn_perm(r[5], r[4], selp);
        uint32_t p67 = __builtin_amdgcn_perm(r[7], r[6], selp);
        uint32_t lo = __builtin_amdgcn_perm(p23, p01, 0x05040100u) & gm;
        uint32_t hi = __builtin_amdgcn_perm(p67, p45, 0x05040100u) & gm;
        uint32_t w[4];
#pragma unroll
        for (int p = 0; p < 4; ++p){
          const uint32_t src = (p < 2) ? lo : hi;
          const uint32_t b0 = (src >> ((p & 1) * 16)) & 0xFFu;
          const uint32_t b1 = (src >> ((p & 1) * 16 + 8)) & 0xFFu;
          w[p] = (b0 ? 0x3F80u : 0u) | (b1 ? 0x3F800000u : 0u);
        }
        Lds.s.frag[kh*128 + t*32 + n4*4 + j] = make_uint4(w[0], w[1], w[2], w[3]);
      }
    }
    __syncthreads();
    if (kti < 7) stage1(kt + 64);

    uint4 A[3][2][4];
#pragma unroll
    for (int s = 0; s < 3; ++s)
#pragma unroll
      for (int ks = 0; ks < 4; ++ks)
#pragma unroll
        for (int rt = 0; rt < 2; ++rt){
          const size_t idx = (size_t)(s*64 + (kti*4 + ks)*2 + (lane >> 5))*512
                           + d0 + wr*64 + rt*32 + (lane & 31);
          A[s][rt][ks] = *(const uint4*)(WF + idx * 16);
        }

#pragma unroll
    for (int ks = 0; ks < 4; ++ks){
#pragma unroll
      for (int ct = 0; ct < 2; ++ct){
        const int fb = wc*64 + ct*32 + (lane & 31);
        bf16x8 bb = asbf(Lds.s.frag[(ks*2 + (lane >> 5))*128 + fb]);
        acc[0][ct] = MFMA_B16(asbf(A[0][0][ks]), bb, acc[0][ct]);
        acc[1][ct] = MFMA_B16(asbf(A[0][1][ks]), bb, acc[1][ct]);
        acc[0][ct] = MFMA_B16(asbf(A[1][0][ks]), bb, acc[0][ct]);
        acc[1][ct] = MFMA_B16(asbf(A[1][1][ks]), bb, acc[1][ct]);
        acc[0][ct] = MFMA_B16(asbf(A[2][0][ks]), bb, acc[0][ct]);
        acc[1][ct] = MFMA_B16(asbf(A[2][1][ks]), bb, acc[1][ct]);
      }
    }
  }

  __syncthreads();
#pragma unroll
  for (int rt = 0; rt < 2; ++rt)
#pragma unroll
    for (int ct = 0; ct < 2; ++ct)
#pragma unroll
      for (int r = 0; r < 16; ++r){
        const int row = wr*64 + rt*32 + (r & 3) + ((r >> 2) << 3) + ((lane >> 5) << 2);
        const int col = wc*64 + ct*32 + (lane & 31);
        Lds.y[row*129 + col] = acc[rt][ct][r];
      }
  __syncthreads();

  const int d = tid & 127, nh = tid >> 7;
  const int dg = d0 + d;
  const float bs = bias[dg];
  const float inv = gamma[dg] * (1.0f / sqrtf(var[dg] + 1e-5f));
  const float mu = mean[dg], be = beta[dg];
#pragma unroll
  for (int jc = 0; jc < 4; ++jc){
    float o[TT][4];
#pragma unroll
    for (int jj = 0; jj < 4; ++jj){
      const int j = jc*4 + jj;
      float v = 0.f;
#pragma unroll
      for (int t = 0; t < TT; ++t){
        float y = Lds.y[d*129 + t*32 + nh*16 + j];
        y = ((y + bs) - mu) * inv + be;
        v += (y - v) * 0.5f;
        const bool s = (v >= 1.0f);
        if (s) v = 0.f;
        o[t][jj] = s ? 1.f : 0.f;
      }
    }
#pragma unroll
    for (int t = 0; t < TT; ++t)
      *(float4*)&O[((size_t)(t*BB + b)*CC + dg)*NN + n0 + nh*16 + jc*4] =
          make_float4(o[t][0], o[t][1], o[t][2], o[t][3]);
  }
}

// ---------------------------------------------------------------------------
extern "C" void kernel_launch(void* const* d_in, const int* in_sizes, int n_in,
                              void* d_out, int out_size, void* d_ws, size_t ws_size,
                              hipStream_t stream)
{
  const float* q   = (const float*)d_in[0];
  const float* k   = (const float*)d_in[1];
  const float* qw  = (const float*)d_in[2];
  const float* kw  = (const float*)d_in[3];
  const float* pw  = (const float*)d_in[4];
  const float* pb  = (const float*)d_in[5];
  const float* qg  = (const float*)d_in[6];
  const float* qbt = (const float*)d_in[7];
  const float* qm  = (const float*)d_in[8];
  const float* qv  = (const float*)d_in[9];
  const float* kg  = (const float*)d_in[10];
  const float* kbt = (const float*)d_in[11];
  const float* km  = (const float*)d_in[12];
  const float* kv  = (const float*)d_in[13];
  const float* pg  = (const float*)d_in[14];
  const float* pbt = (const float*)d_in[15];
  const float* pm  = (const float*)d_in[16];
  const float* pv  = (const float*)d_in[17];

  u8* WFq = (u8*)d_ws;
  u8* WFk = WFq + WF_BYTES;
  u8* WFp = WFk + WF_BYTES;
  u8* Sq  = WFp + WF_BYTES;
  u8* Sk  = Sq + SZ_SPIKE;
  u8* Aa  = Sk + SZ_SPIKE;

  k_prep<<<dim3(128, 3), 256, 0, stream>>>(qw, kw, pw, WFq, WFk, WFp);
  dim3 g(4, 32, 8);
  k_qk<<<g, 256, 0, stream>>>(q, WFq, qg, qbt, qm, qv, Sq);
  k_qk<<<g, 256, 0, stream>>>(k, WFk, kg, kbt, km, kv, Sk);
  k_attn<<<dim3(1, HH, TT*BB), 256, 0, stream>>>(Sq, Aa);
  k_proj<<<g, 256, 0, stream>>>(Sk, Aa, WFp, pb, pg, pbt, pm, pv, (float*)d_out);
}

// Round 3
// 244.069 us; speedup vs baseline: 2.6088x; 1.3311x over previous
//
#include <hip/hip_runtime.h>
#include <hip/hip_fp16.h>
#include <stdint.h>

#define TT 4
#define BB 8
#define CC 512
#define NN 1024
#define HH 8

typedef unsigned char u8;
typedef _Float16 f16x8 __attribute__((ext_vector_type(8)));
typedef float f32x16 __attribute__((ext_vector_type(16)));

#define WF_BYTES ((size_t)2*64*512*16)        /* 1 MiB per weight (fp16x2 frags) */
#define XF_BYTES ((size_t)2*TT*BB*64*NN*16)   /* 64 MiB per activation */
#define SZ_SPIKE ((size_t)TT*BB*CC*NN)        /* 16 MiB */

union U4H { uint4 u; f16x8 v; };
__device__ __forceinline__ f16x8 ash(uint4 u){ U4H x; x.u = u; return x.v; }

#define MFMA_F16(a,b,c) __builtin_amdgcn_mfma_f32_32x32x16_f16((a),(b),(c),0,0,0)

__device__ __forceinline__ void gld_lds16(const void* g, void* l){
  __builtin_amdgcn_global_load_lds((const __attribute__((address_space(1))) void*)g,
                                   (__attribute__((address_space(3))) void*)l, 16, 0, 0);
}
__device__ __forceinline__ void gld_lds4(const void* g, void* l){
  __builtin_amdgcn_global_load_lds((const __attribute__((address_space(1))) void*)g,
                                   (__attribute__((address_space(3))) void*)l, 4, 0, 0);
}

// fp16x2 split of a scaled fp32: xs = h + m + r, |r| <= 2^-24 |xs| (RNE,RNE)
__device__ __forceinline__ void split16(float xs, uint32_t& h, uint32_t& m){
  __half hh = __float2half(xs);
  float hf = __half2float(hh);
  __half mm = __float2half(xs - hf);
  h = __half_as_ushort(hh);
  m = __half_as_ushort(mm);
}

// ---------------------------------------------------------------------------
// prep: W [512x512] fp32 -> fp16x2 fragments (scale 64), layout [s][kh64][row512]x16B
// grid (128,3) x 256
// ---------------------------------------------------------------------------
__global__ __launch_bounds__(256)
void k_prep(const float* __restrict__ W0, const float* __restrict__ W1,
            const float* __restrict__ W2,
            u8* __restrict__ D0, u8* __restrict__ D1, u8* __restrict__ D2)
{
  const int which = blockIdx.y;
  const float* W = (which == 0) ? W0 : (which == 1) ? W1 : W2;
  u8* D = (which == 0) ? D0 : (which == 1) ? D1 : D2;
  const int tg  = blockIdx.x * 256 + threadIdx.x;
  const int row = tg >> 6;
  const int kh  = tg & 63;
  uint32_t Hw[4], Mw[4];
#pragma unroll
  for (int p = 0; p < 4; ++p){
    uint32_t h0, m0, h1, m1;
    split16(W[row * CC + kh * 8 + 2*p    ] * 64.0f, h0, m0);
    split16(W[row * CC + kh * 8 + 2*p + 1] * 64.0f, h1, m1);
    Hw[p] = h0 | (h1 << 16);
    Mw[p] = m0 | (m1 << 16);
  }
  *(uint4*)(D + ((size_t)(0*64 + kh)*512 + row) * 16) = make_uint4(Hw[0],Hw[1],Hw[2],Hw[3]);
  *(uint4*)(D + ((size_t)(1*64 + kh)*512 + row) * 16) = make_uint4(Mw[0],Mw[1],Mw[2],Mw[3]);
}

// ---------------------------------------------------------------------------
// splitx: X fp32 [T,B,C,N] -> fp16x2 frags (scale 512),
// uint4 at ((s*T+t)*B+b)*64+kh)*N + n  holds x[t,b,kh*8+e,n] e=0..7
// grid (16 nchunk, 16 khgrp, 64 z) x 256   (z<32: q, else k)
// ---------------------------------------------------------------------------
__global__ __launch_bounds__(256)
void k_splitx(const float* __restrict__ Q, const float* __restrict__ K,
              u8* __restrict__ XFq, u8* __restrict__ XFk)
{
  const int z = blockIdx.z;
  const float* X = (z < 32) ? Q : K;
  u8* XF = (z < 32) ? XFq : XFk;
  const int tb = z & 31, t = tb >> 3, b = tb & 7;
  const int nl = threadIdx.x & 63, khl = threadIdx.x >> 6;
  const int kh = blockIdx.y * 4 + khl;
  const int n  = blockIdx.x * 64 + nl;
  const float* xp = X + ((size_t)(t*BB + b)*CC + kh*8)*NN + n;
  uint32_t Hw[4], Mw[4];
#pragma unroll
  for (int p = 0; p < 4; ++p){
    uint32_t h0, m0, h1, m1;
    split16(xp[(size_t)(2*p    )*NN] * 512.0f, h0, m0);
    split16(xp[(size_t)(2*p + 1)*NN] * 512.0f, h1, m1);
    Hw[p] = h0 | (h1 << 16);
    Mw[p] = m0 | (m1 << 16);
  }
  const size_t i0 = ((size_t)((0*TT + t)*BB + b)*64 + kh)*NN + n;
  const size_t i1 = ((size_t)((1*TT + t)*BB + b)*64 + kh)*NN + n;
  *(uint4*)(XF + i0*16) = make_uint4(Hw[0],Hw[1],Hw[2],Hw[3]);
  *(uint4*)(XF + i1*16) = make_uint4(Mw[0],Mw[1],Mw[2],Mw[3]);
}

// ---------------------------------------------------------------------------
// q/k path (merged): fp16x2 GEMM (3 passes) + BN + LIF -> u8 spikes
// block 256 (4 waves, 2x2 of 64x64); tile 128d x (4t x 32n)
// grid 2048 1-D, XCD-chunked swizzle; lg = ((path*8+b)*32+n0i)*4+d0i
// ---------------------------------------------------------------------------
union LdsQK {
  uint4 frag[2][2*8*128];   // [buf][(s*8+kh)*128 + col], 2 x 32 KiB
  float y[128*129];         // 64.5 KiB
};

__global__ __launch_bounds__(256, 2)
void k_qk(const u8* __restrict__ XFq, const u8* __restrict__ XFk,
          const u8* __restrict__ WFq, const u8* __restrict__ WFk,
          const float* __restrict__ qg, const float* __restrict__ qb,
          const float* __restrict__ qm, const float* __restrict__ qv,
          const float* __restrict__ kg, const float* __restrict__ kb,
          const float* __restrict__ km, const float* __restrict__ kv,
          u8* __restrict__ Sq, u8* __restrict__ Sk)
{
  __shared__ LdsQK Lds;
  const int hw = blockIdx.x;
  const int lg = (hw & 7) * 256 + (hw >> 3);
  const int path = lg >> 10;
  const int b  = (lg >> 7) & 7;
  const int n0 = ((lg >> 2) & 31) << 5;
  const int d0 = (lg & 3) << 7;
  const u8* XF = path ? XFk : XFq;
  const u8* WF = path ? WFk : WFq;

  const int tid = threadIdx.x;
  const int lane = tid & 63;
  const int wid  = tid >> 6;
  const int wr = wid >> 1, wc = wid & 1;

  f32x16 acc[2][2];
#pragma unroll
  for (int i = 0; i < 2; ++i)
#pragma unroll
    for (int j = 0; j < 2; ++j)
#pragma unroll
      for (int r = 0; r < 16; ++r) acc[i][j][r] = 0.0f;

  // stage K-tile kti into frag[buf]: 32 wave-loads, 8 per wave
  auto stage = [&](int bufi, int kti){
#pragma unroll
    for (int i = 0; i < 8; ++i){
      const int w = wid*8 + i;
      const int r = w >> 1;            // s*8 + khl
      const int h = w & 1;
      const int s = r >> 3, khl = r & 7;
      const int col = h*64 + lane;
      const int t = col >> 5, n = col & 31;
      const u8* g = XF + (((size_t)((s*TT + t)*BB + b)*64 + kti*8 + khl)*NN + n0 + n)*16;
      gld_lds16(g, (void*)&Lds.frag[bufi][r*128 + h*64]);
    }
  };

  stage(0, 0);
  int buf = 0;
  for (int kti = 0; kti < 8; ++kti){
    asm volatile("s_waitcnt vmcnt(0)" ::: "memory");
    __syncthreads();

    // A fragments (issued BEFORE stage loads: vmcnt FIFO keeps prefetch alive)
    uint4 A[2][2][4];
#pragma unroll
    for (int s = 0; s < 2; ++s)
#pragma unroll
      for (int rt = 0; rt < 2; ++rt)
#pragma unroll
        for (int ks = 0; ks < 4; ++ks){
          const size_t idx = (size_t)(s*64 + kti*8 + ks*2 + (lane >> 5))*512
                           + d0 + wr*64 + rt*32 + (lane & 31);
          A[s][rt][ks] = *(const uint4*)(WF + idx * 16);
        }

    if (kti < 7) stage(buf ^ 1, kti + 1);

#pragma unroll
    for (int ks = 0; ks < 4; ++ks){
#pragma unroll
      for (int ct = 0; ct < 2; ++ct){
        const int fb = wc*64 + ct*32 + (lane & 31);
        const int kbi = ks*2 + (lane >> 5);
        f16x8 bh = ash(Lds.frag[buf][(0*8 + kbi)*128 + fb]);
        f16x8 bm = ash(Lds.frag[buf][(1*8 + kbi)*128 + fb]);
        acc[0][ct] = MFMA_F16(ash(A[0][0][ks]), bh, acc[0][ct]);  // Wh*Xh
        acc[1][ct] = MFMA_F16(ash(A[0][1][ks]), bh, acc[1][ct]);
        acc[0][ct] = MFMA_F16(ash(A[1][0][ks]), bh, acc[0][ct]);  // Wm*Xh
        acc[1][ct] = MFMA_F16(ash(A[1][1][ks]), bh, acc[1][ct]);
        acc[0][ct] = MFMA_F16(ash(A[0][0][ks]), bm, acc[0][ct]);  // Wh*Xm
        acc[1][ct] = MFMA_F16(ash(A[0][1][ks]), bm, acc[1][ct]);
      }
    }
    buf ^= 1;
  }

  __syncthreads();   // frags dead; reuse LDS as y tile (undo 512*64 scale)
#pragma unroll
  for (int rt = 0; rt < 2; ++rt)
#pragma unroll
    for (int ct = 0; ct < 2; ++ct)
#pragma unroll
      for (int r = 0; r < 16; ++r){
        const int row = wr*64 + rt*32 + (r & 3) + ((r >> 2) << 3) + ((lane >> 5) << 2);
        const int col = wc*64 + ct*32 + (lane & 31);
        Lds.y[row*129 + col] = acc[rt][ct][r] * (1.0f/32768.0f);
      }
  __syncthreads();

  const float* gamma = path ? kg : qg;
  const float* beta  = path ? kb : qb;
  const float* mean  = path ? km : qm;
  const float* var   = path ? kv : qv;
  u8* S = path ? Sk : Sq;

  const int d = tid & 127, nh = tid >> 7;
  const int dg = d0 + d;
  const float inv = gamma[dg] * (1.0f / sqrtf(var[dg] + 1e-5f));
  const float mu = mean[dg], be = beta[dg];
  uint32_t pk[TT][4] = {{0,0,0,0},{0,0,0,0},{0,0,0,0},{0,0,0,0}};
#pragma unroll
  for (int j = 0; j < 16; ++j){
    float v = 0.f;
#pragma unroll
    for (int t = 0; t < TT; ++t){
      float y = Lds.y[d*129 + t*32 + nh*16 + j];
      y = (y - mu) * inv + be;
      v += (y - v) * 0.5f;
      uint32_t s = (v >= 1.0f) ? 1u : 0u;
      if (s) v = 0.f;
      pk[t][j >> 2] |= s << ((j & 3) * 8);
    }
  }
#pragma unroll
  for (int t = 0; t < TT; ++t)
    *(uint4*)&S[((size_t)(t*BB + b)*CC + dg)*NN + n0 + nh*16] =
        make_uint4(pk[t][0], pk[t][1], pk[t][2], pk[t][3]);
}

// ---------------------------------------------------------------------------
// attn gate: byte-OR over the 64 channels of each head (exact LIF equivalent)
// ---------------------------------------------------------------------------
__global__ __launch_bounds__(256)
void k_attn(const u8* __restrict__ Sq, u8* __restrict__ A)
{
  const int n4 = threadIdx.x;
  const int h  = blockIdx.y;
  const int tb = blockIdx.z;
  const u8* p = Sq + ((size_t)tb * CC + (h << 6)) * NN + (n4 << 2);
  uint32_t acc = 0;
#pragma unroll 8
  for (int d = 0; d < 64; ++d)
    acc |= *(const uint32_t*)(p + (size_t)d * NN);
  *(uint32_t*)(A + ((size_t)tb * HH + h) * NN + (n4 << 2)) = acc;
}

// ---------------------------------------------------------------------------
// proj: x = (attn & k_s) exact in fp16; W fp16x2 -> 2 passes; +bias,BN,LIF
// grid 1024 1-D swizzled
// ---------------------------------------------------------------------------
union LdsPJ {
  struct { u8 xu[TT*64*32]; uint4 frag[8*128]; } s;  // 8 KiB + 16 KiB
  float y[128*129];
};

__global__ __launch_bounds__(256, 2)
void k_proj(const u8* __restrict__ Sk, const u8* __restrict__ Ag,
            const u8* __restrict__ WF, const float* __restrict__ bias,
            const float* __restrict__ gamma, const float* __restrict__ beta,
            const float* __restrict__ mean, const float* __restrict__ var,
            float* __restrict__ O)
{
  __shared__ LdsPJ Lds;
  const int hw = blockIdx.x;
  const int lg = (hw & 7) * 128 + (hw >> 3);
  const int b  = lg >> 7;
  const int n0 = ((lg >> 2) & 31) << 5;
  const int d0 = (lg & 3) << 7;

  const int tid = threadIdx.x;
  const int lane = tid & 63;
  const int wid  = tid >> 6;
  const int wr = wid >> 1, wc = wid & 1;

  f32x16 acc[2][2];
#pragma unroll
  for (int i = 0; i < 2; ++i)
#pragma unroll
    for (int j = 0; j < 2; ++j)
#pragma unroll
      for (int r = 0; r < 16; ++r) acc[i][j][r] = 0.0f;

  auto stage1 = [&](int kt){
    const u8* xb = Sk + ((size_t)(wid*BB + b)*CC + kt)*NN + n0 + ((lane & 7) << 2);
#pragma unroll
    for (int i = 0; i < 8; ++i){
      const u8* g = xb + (size_t)(i*8 + (lane >> 3)) * NN;
      gld_lds4(g, (void*)&Lds.s.xu[(wid*64 + i*8) * 32]);
    }
  };

  stage1(0);

  for (int kti = 0; kti < 8; ++kti){
    asm volatile("s_waitcnt vmcnt(0)" ::: "memory");
    __syncthreads();

    { // stage2: byte transpose + gate + u8 -> fp16 {0,1}
      const int kh = tid >> 5;
      const int t  = (tid >> 3) & 3;
      const int n4 = tid & 7;
      uint32_t g32 = *(const uint32_t*)(Ag + ((size_t)(t*BB + b)*HH + kti)*NN + n0 + n4*4);
      uint32_t r[8];
#pragma unroll
      for (int c = 0; c < 8; ++c)
        r[c] = *(const uint32_t*)&Lds.s.xu[(t*64 + kh*8 + c)*32 + n4*4];
#pragma unroll
      for (int j = 0; j < 4; ++j){
        const uint32_t gm   = __builtin_amdgcn_perm(g32, g32, (uint32_t)j * 0x01010101u);
        const uint32_t selp = (uint32_t)j | (((uint32_t)j + 4u) << 8);
        uint32_t p01 = __builtin_amdgcn_perm(r[1], r[0], selp);
        uint32_t p23 = __builtin_amdgcn_perm(r[3], r[2], selp);
        uint32_t p45 = __builtin_amdgcn_perm(r[5], r[4], selp);
        uint32_t p67 = __builtin_amdgcn_perm(r[7], r[6], selp);
        uint32_t lo = __builtin_amdgcn_perm(p23, p01, 0x05040100u) & gm;
        uint32_t hi = __builtin_amdgcn_perm(p67, p45, 0x05040100u) & gm;
        uint32_t w[4];
#pragma unroll
        for (int p = 0; p < 4; ++p){
          const uint32_t src = (p < 2) ? lo : hi;
          const uint32_t b0 = (src >> ((p & 1) * 16)) & 0xFFu;
          const uint32_t b1 = (src >> ((p & 1) * 16 + 8)) & 0xFFu;
          w[p] = (b0 ? 0x3C00u : 0u) | (b1 ? 0x3C000000u : 0u);
        }
        Lds.s.frag[kh*128 + t*32 + n4*4 + j] = make_uint4(w[0], w[1], w[2], w[3]);
      }
    }
    __syncthreads();

    uint4 A[2][2][4];
#pragma unroll
    for (int s = 0; s < 2; ++s)
#pragma unroll
      for (int rt = 0; rt < 2; ++rt)
#pragma unroll
        for (int ks = 0; ks < 4; ++ks){
          const size_t idx = (size_t)(s*64 + kti*8 + ks*2 + (lane >> 5))*512
                           + d0 + wr*64 + rt*32 + (lane & 31);
          A[s][rt][ks] = *(const uint4*)(WF + idx * 16);
        }

    if (kti < 7) stage1((kti + 1) * 64);

#pragma unroll
    for (int ks = 0; ks < 4; ++ks){
#pragma unroll
      for (int ct = 0; ct < 2; ++ct){
        const int fb = wc*64 + ct*32 + (lane & 31);
        f16x8 bb = ash(Lds.s.frag[(ks*2 + (lane >> 5))*128 + fb]);
        acc[0][ct] = MFMA_F16(ash(A[0][0][ks]), bb, acc[0][ct]);
        acc[1][ct] = MFMA_F16(ash(A[0][1][ks]), bb, acc[1][ct]);
        acc[0][ct] = MFMA_F16(ash(A[1][0][ks]), bb, acc[0][ct]);
        acc[1][ct] = MFMA_F16(ash(A[1][1][ks]), bb, acc[1][ct]);
      }
    }
  }

  __syncthreads();
#pragma unroll
  for (int rt = 0; rt < 2; ++rt)
#pragma unroll
    for (int ct = 0; ct < 2; ++ct)
#pragma unroll
      for (int r = 0; r < 16; ++r){
        const int row = wr*64 + rt*32 + (r & 3) + ((r >> 2) << 3) + ((lane >> 5) << 2);
        const int col = wc*64 + ct*32 + (lane & 31);
        Lds.y[row*129 + col] = acc[rt][ct][r] * 0.015625f;   // / 64
      }
  __syncthreads();

  const int d = tid & 127, nh = tid >> 7;
  const int dg = d0 + d;
  const float bs = bias[dg];
  const float inv = gamma[dg] * (1.0f / sqrtf(var[dg] + 1e-5f));
  const float mu = mean[dg], be = beta[dg];
#pragma unroll
  for (int jc = 0; jc < 4; ++jc){
    float o[TT][4];
#pragma unroll
    for (int jj = 0; jj < 4; ++jj){
      const int j = jc*4 + jj;
      float v = 0.f;
#pragma unroll
      for (int t = 0; t < TT; ++t){
        float y = Lds.y[d*129 + t*32 + nh*16 + j];
        y = ((y + bs) - mu) * inv + be;
        v += (y - v) * 0.5f;
        const bool s = (v >= 1.0f);
        if (s) v = 0.f;
        o[t][jj] = s ? 1.f : 0.f;
      }
    }
#pragma unroll
    for (int t = 0; t < TT; ++t)
      *(float4*)&O[((size_t)(t*BB + b)*CC + dg)*NN + n0 + nh*16 + jc*4] =
          make_float4(o[t][0], o[t][1], o[t][2], o[t][3]);
  }
}

// ---------------------------------------------------------------------------
extern "C" void kernel_launch(void* const* d_in, const int* in_sizes, int n_in,
                              void* d_out, int out_size, void* d_ws, size_t ws_size,
                              hipStream_t stream)
{
  const float* q   = (const float*)d_in[0];
  const float* k   = (const float*)d_in[1];
  const float* qw  = (const float*)d_in[2];
  const float* kw  = (const float*)d_in[3];
  const float* pw  = (const float*)d_in[4];
  const float* pb  = (const float*)d_in[5];
  const float* qg  = (const float*)d_in[6];
  const float* qbt = (const float*)d_in[7];
  const float* qm  = (const float*)d_in[8];
  const float* qv  = (const float*)d_in[9];
  const float* kg  = (const float*)d_in[10];
  const float* kbt = (const float*)d_in[11];
  const float* km  = (const float*)d_in[12];
  const float* kv  = (const float*)d_in[13];
  const float* pg  = (const float*)d_in[14];
  const float* pbt = (const float*)d_in[15];
  const float* pm  = (const float*)d_in[16];
  const float* pv  = (const float*)d_in[17];

  u8* WFq = (u8*)d_ws;
  u8* WFk = WFq + WF_BYTES;
  u8* WFp = WFk + WF_BYTES;
  u8* XFq = WFp + WF_BYTES;
  u8* XFk = XFq + XF_BYTES;
  u8* Sq  = XFk + XF_BYTES;
  u8* Sk  = Sq + SZ_SPIKE;
  u8* Aa  = Sk + SZ_SPIKE;
  const size_t need = 3*WF_BYTES + 2*XF_BYTES + 2*SZ_SPIKE + (size_t)TT*BB*HH*NN;
  if (ws_size < need) return;   // fail loudly (poison stays) rather than corrupt

  k_prep<<<dim3(128, 3), 256, 0, stream>>>(qw, kw, pw, WFq, WFk, WFp);
  k_splitx<<<dim3(16, 16, 64), 256, 0, stream>>>(q, k, XFq, XFk);
  k_qk<<<2048, 256, 0, stream>>>(XFq, XFk, WFq, WFk,
                                 qg, qbt, qm, qv, kg, kbt, km, kv, Sq, Sk);
  k_attn<<<dim3(1, HH, TT*BB), 256, 0, stream>>>(Sq, Aa);
  k_proj<<<1024, 256, 0, stream>>>(Sk, Aa, WFp, pb, pg, pbt, pm, pv, (float*)d_out);
}

// Round 4
// 226.012 us; speedup vs baseline: 2.8172x; 1.0799x over previous
//
#include <hip/hip_runtime.h>
#include <hip/hip_fp16.h>
#include <stdint.h>

#define TT 4
#define BB 8
#define CC 512
#define NN 1024
#define HH 8

typedef unsigned char u8;
typedef _Float16 f16x8 __attribute__((ext_vector_type(8)));
typedef float f32x16 __attribute__((ext_vector_type(16)));

#define WF_BYTES ((size_t)2*64*512*16)        /* 1 MiB per weight (fp16x2 frags) */
#define XF_BYTES ((size_t)8*32*262144)        /* 64 MiB per activation (panels) */
#define SZ_SPIKE ((size_t)TT*BB*CC*NN)        /* 16 MiB */
#define SZ_GATE  ((size_t)TT*BB*HH*NN)        /* 256 KiB */

union U4H { uint4 u; f16x8 v; };
__device__ __forceinline__ f16x8 ash(uint4 u){ U4H x; x.u = u; return x.v; }

#define MFMA_F16(a,b,c) __builtin_amdgcn_mfma_f32_32x32x16_f16((a),(b),(c),0,0,0)

__device__ __forceinline__ void gld_lds16(const void* g, void* l){
  __builtin_amdgcn_global_load_lds((const __attribute__((address_space(1))) void*)g,
                                   (__attribute__((address_space(3))) void*)l, 16, 0, 0);
}
__device__ __forceinline__ void gld_lds4(const void* g, void* l){
  __builtin_amdgcn_global_load_lds((const __attribute__((address_space(1))) void*)g,
                                   (__attribute__((address_space(3))) void*)l, 4, 0, 0);
}

#define WAITVM(N) asm volatile("s_waitcnt vmcnt(" #N ")" ::: "memory")
#define WAITLGKM0 asm volatile("s_waitcnt lgkmcnt(0)" ::: "memory")
#define SBAR() __builtin_amdgcn_s_barrier()

// fp16x2 split of a scaled fp32: xs = h + m + r, |r| <= 2^-24 |xs|
__device__ __forceinline__ void split16(float xs, uint32_t& h, uint32_t& m){
  __half hh = __float2half(xs);
  float hf = __half2float(hh);
  __half mm = __float2half(xs - hf);
  h = __half_as_ushort(hh);
  m = __half_as_ushort(mm);
}

// ---------------------------------------------------------------------------
// prep: W [512x512] fp32 -> fp16x2 frags (scale 64), layout [s][kbg64][row512]x16B
// ---------------------------------------------------------------------------
__global__ __launch_bounds__(256)
void k_prep(const float* __restrict__ W0, const float* __restrict__ W1,
            const float* __restrict__ W2,
            u8* __restrict__ D0, u8* __restrict__ D1, u8* __restrict__ D2)
{
  const int which = blockIdx.y;
  const float* W = (which == 0) ? W0 : (which == 1) ? W1 : W2;
  u8* D = (which == 0) ? D0 : (which == 1) ? D1 : D2;
  const int tg  = blockIdx.x * 256 + threadIdx.x;
  const int row = tg >> 6;
  const int kh  = tg & 63;
  uint32_t Hw[4], Mw[4];
#pragma unroll
  for (int p = 0; p < 4; ++p){
    uint32_t h0, m0, h1, m1;
    split16(W[row * CC + kh * 8 + 2*p    ] * 64.0f, h0, m0);
    split16(W[row * CC + kh * 8 + 2*p + 1] * 64.0f, h1, m1);
    Hw[p] = h0 | (h1 << 16);
    Mw[p] = m0 | (m1 << 16);
  }
  *(uint4*)(D + ((size_t)(0*64 + kh)*512 + row) * 16) = make_uint4(Hw[0],Hw[1],Hw[2],Hw[3]);
  *(uint4*)(D + ((size_t)(1*64 + kh)*512 + row) * 16) = make_uint4(Mw[0],Mw[1],Mw[2],Mw[3]);
}

// ---------------------------------------------------------------------------
// splitx: X fp32 -> fp16x2 panels. Panel (b,n0i) = 256 KiB:
//   uint4[row 128][col 128], row = h*8 + s*4 + khl (h=k32-tile), col = t*32+nn
// grid (4, 16, 64) x 256; thread handles 4 n, 8 k-rows
// ---------------------------------------------------------------------------
__global__ __launch_bounds__(256)
void k_splitx(const float* __restrict__ Q, const float* __restrict__ K,
              u8* __restrict__ XFq, u8* __restrict__ XFk)
{
  const int z = blockIdx.z;
  const float* X = (z < 32) ? Q : K;
  u8* XF = (z < 32) ? XFq : XFk;
  const int tb = z & 31, t = tb >> 3, b = tb & 7;
  const int n4 = threadIdx.x & 63, khl = threadIdx.x >> 6;
  const int kh = blockIdx.y * 4 + khl;          // [0,64) : 8-k group
  const int n  = blockIdx.x * 256 + n4 * 4;
  const float* xp = X + ((size_t)((t*BB + b)*CC) + (size_t)kh*8)*NN + n;
  float4 xv[8];
#pragma unroll
  for (int p = 0; p < 8; ++p) xv[p] = *(const float4*)(xp + (size_t)p * NN);

  u8* dst = XF + ((size_t)(b*32 + (n >> 5)) << 18)
               + ((size_t)((kh >> 2)*8 + (kh & 3))*128 + t*32 + (n & 31)) * 16;
#pragma unroll
  for (int j = 0; j < 4; ++j){
    uint32_t Hw[4], Mw[4];
#pragma unroll
    for (int wi = 0; wi < 4; ++wi){
      const float* f0 = (const float*)&xv[2*wi];
      const float* f1 = (const float*)&xv[2*wi + 1];
      uint32_t h0, m0, h1, m1;
      split16(f0[j] * 512.0f, h0, m0);
      split16(f1[j] * 512.0f, h1, m1);
      Hw[wi] = h0 | (h1 << 16);
      Mw[wi] = m0 | (m1 << 16);
    }
    *(uint4*)(dst + (size_t)j*16)        = make_uint4(Hw[0],Hw[1],Hw[2],Hw[3]);
    *(uint4*)(dst + 8192 + (size_t)j*16) = make_uint4(Mw[0],Mw[1],Mw[2],Mw[3]); // s=1: +4 rows
  }
}

// ---------------------------------------------------------------------------
// q/k path: fp16x2 GEMM (3 passes) + BN + LIF.
//   k-path -> u8 spikes Sk;  q-path -> head-OR gate Aa (k_attn folded in)
// 4 waves x (32d x 128col=4t*32n); K=32 half-tiles, ring-3 LDS, counted vmcnt
// grid 2048, XCD-chunked swizzle
// ---------------------------------------------------------------------------
__global__ __launch_bounds__(256, 3)
void k_qk(const u8* __restrict__ XFq, const u8* __restrict__ XFk,
          const u8* __restrict__ WFq, const u8* __restrict__ WFk,
          const float* __restrict__ qg, const float* __restrict__ qb,
          const float* __restrict__ qm, const float* __restrict__ qv,
          const float* __restrict__ kg, const float* __restrict__ kb,
          const float* __restrict__ km, const float* __restrict__ kv,
          u8* __restrict__ Sk, u8* __restrict__ Aa)
{
  __shared__ uint4 frag[3][1024];               // 3 x 16 KiB ring

  const int hw = blockIdx.x;
  const int lg = (hw & 7) * 256 + (hw >> 3);
  const int path = lg >> 10;
  const int b   = (lg >> 7) & 7;
  const int n0i = (lg >> 2) & 31;
  const int d0t = lg & 3;
  const int n0 = n0i << 5, d0 = d0t << 7;
  const u8* XF = path ? XFk : XFq;
  const u8* WF = path ? WFk : WFq;

  const int tid = threadIdx.x, lane = tid & 63, wid = tid >> 6;
  const int hi = lane >> 5, ln31 = lane & 31;
  const u8* panel = XF + ((size_t)(b*32 + n0i) << 18);
  const int rowA = d0 + wid*32 + ln31;

  f32x16 acc[4];
#pragma unroll
  for (int t = 0; t < 4; ++t)
#pragma unroll
    for (int r = 0; r < 16; ++r) acc[t][r] = 0.0f;

  uint4 A0[4], A1[4];

  auto stageX = [&](int h, int buf){
#pragma unroll
    for (int i = 0; i < 4; ++i){
      const int c = wid*4 + i;
      gld_lds16(panel + ((size_t)h << 14) + ((size_t)c << 10) + (size_t)lane*16,
                (void*)&frag[buf][c*64]);
    }
  };
  auto loadA = [&](uint4* A, int h){
#pragma unroll
    for (int s = 0; s < 2; ++s)
#pragma unroll
      for (int ks = 0; ks < 2; ++ks)
        A[s*2 + ks] = *(const uint4*)(WF +
            ((size_t)(s*64 + h*4 + ks*2 + hi)*512 + rowA) * 16);
  };
  auto mstep = [&](uint4* A, int hb){
#pragma unroll
    for (int ks = 0; ks < 2; ++ks){
      const int kb = ks*2 + hi;
#pragma unroll
      for (int ct = 0; ct < 4; ++ct){
        const int fb = ct*32 + ln31;
        f16x8 bh = ash(frag[hb][kb*128 + fb]);        // s=0 rows
        f16x8 bm = ash(frag[hb][(4 + kb)*128 + fb]);  // s=1 rows
        acc[ct] = MFMA_F16(ash(A[ks]),     bh, acc[ct]);  // Wh*Xh
        acc[ct] = MFMA_F16(ash(A[2 + ks]), bh, acc[ct]);  // Wm*Xh
        acc[ct] = MFMA_F16(ash(A[ks]),     bm, acc[ct]);  // Wh*Xm
      }
    }
  };

#define QK_BODY(H, VM) { \
    WAITVM(VM); SBAR(); \
    if ((H) < 15) loadA(((H)&1) ? A0 : A1, (H)+1); \
    if ((H) < 14) stageX((H)+2, ((H)+2)%3); \
    mstep(((H)&1) ? A1 : A0, (H)%3); }

  stageX(0, 0); stageX(1, 1); loadA(A0, 0);
  QK_BODY(0,8)  QK_BODY(1,8)  QK_BODY(2,8)  QK_BODY(3,8)
  QK_BODY(4,8)  QK_BODY(5,8)  QK_BODY(6,8)  QK_BODY(7,8)
  QK_BODY(8,8)  QK_BODY(9,8)  QK_BODY(10,8) QK_BODY(11,8)
  QK_BODY(12,8) QK_BODY(13,8) QK_BODY(14,8) QK_BODY(15,4)
#undef QK_BODY

  const float* gamma = path ? kg : qg;
  const float* beta  = path ? kb : qb;
  const float* mean  = path ? km : qm;
  const float* var   = path ? kv : qv;

  float c1[16], c0[16];
#pragma unroll
  for (int rg = 0; rg < 4; ++rg){
    const int dbase = d0 + wid*32 + rg*8 + hi*4;
    const float4 g4 = *(const float4*)&gamma[dbase];
    const float4 b4 = *(const float4*)&beta[dbase];
    const float4 m4 = *(const float4*)&mean[dbase];
    const float4 v4 = *(const float4*)&var[dbase];
    const float* gp = (const float*)&g4;
    const float* bp = (const float*)&b4;
    const float* mp = (const float*)&m4;
    const float* vp = (const float*)&v4;
#pragma unroll
    for (int j = 0; j < 4; ++j){
      const float inv = gp[j] * (1.0f / sqrtf(vp[j] + 1e-5f));
      c1[rg*4 + j] = inv * (1.0f/32768.0f);
      c0[rg*4 + j] = bp[j] - mp[j]*inv;
    }
  }

  if (path == 1){
#pragma unroll
    for (int rg = 0; rg < 4; ++rg)
#pragma unroll
      for (int j = 0; j < 4; ++j){
        const int r = rg*4 + j;
        const int d = d0 + wid*32 + j + rg*8 + hi*4;
        float v = 0.f;
#pragma unroll
        for (int t = 0; t < 4; ++t){
          const float y = fmaf(acc[t][r], c1[r], c0[r]);
          v = 0.5f*(v + y);
          const bool s = (v >= 1.0f);
          if (s) v = 0.f;
          Sk[((size_t)(t*BB + b)*CC + d)*NN + n0 + ln31] = (u8)s;
        }
      }
  } else {
    uint32_t orb = 0;
#pragma unroll
    for (int rg = 0; rg < 4; ++rg)
#pragma unroll
      for (int j = 0; j < 4; ++j){
        const int r = rg*4 + j;
        float v = 0.f;
#pragma unroll
        for (int t = 0; t < 4; ++t){
          const float y = fmaf(acc[t][r], c1[r], c0[r]);
          v = 0.5f*(v + y);
          const bool s = (v >= 1.0f);
          if (s) v = 0.f;
          orb |= ((uint32_t)s) << t;
        }
      }
    __syncthreads();
    uint32_t* gw = (uint32_t*)&frag[1][0];      // 64 words: [hl2][t][nw]
    if (tid < 64) gw[tid] = 0;
    __syncthreads();
    const int hl2 = wid >> 1;
#pragma unroll
    for (int t = 0; t < 4; ++t)
      if ((orb >> t) & 1)
        atomicOr(&gw[hl2*32 + t*8 + (ln31 >> 2)], 1u << ((ln31 & 3)*8));
    __syncthreads();
    if (tid < 64){
      const int hl = tid >> 5, t = (tid >> 3) & 3, nw = tid & 7;
      *(uint32_t*)(Aa + ((size_t)(t*BB + b)*HH + d0t*2 + hl)*NN + n0 + nw*4) =
          gw[hl*32 + t*8 + nw];
    }
  }
}

// ---------------------------------------------------------------------------
// proj: x = (attn & k_s) exact in fp16; W fp16x2 -> 2 passes; +bias,BN,LIF
// 4 waves x (32d x 128col); K=64 phases, xu ring-3 + single frag, 2 barriers
// grid 1024 swizzled
// ---------------------------------------------------------------------------
__global__ __launch_bounds__(256, 3)
void k_proj(const u8* __restrict__ Sk, const u8* __restrict__ Ag,
            const u8* __restrict__ WF, const float* __restrict__ bias,
            const float* __restrict__ gamma, const float* __restrict__ beta,
            const float* __restrict__ mean, const float* __restrict__ var,
            float* __restrict__ O)
{
  __shared__ u8   xu[3][8192];                  // [t4][k64][n32] per buf
  __shared__ uint4 frag[1024];                  // [kb8][col128]

  const int hw = blockIdx.x;
  const int lg = (hw & 7) * 128 + (hw >> 3);
  const int b   = lg >> 7;
  const int n0i = (lg >> 2) & 31;
  const int d0t = lg & 3;
  const int n0 = n0i << 5, d0 = d0t << 7;

  const int tid = threadIdx.x, lane = tid & 63, wid = tid >> 6;
  const int hi = lane >> 5, ln31 = lane & 31;
  const int rowA = d0 + wid*32 + ln31;

  const int st_kh = tid >> 5, st_t = (tid >> 3) & 3, st_n4 = tid & 7;

  f32x16 acc[4];
#pragma unroll
  for (int t = 0; t < 4; ++t)
#pragma unroll
    for (int r = 0; r < 16; ++r) acc[t][r] = 0.0f;

  uint4 Ap[8];
  uint32_t gword[8];
#pragma unroll
  for (int p = 0; p < 8; ++p)
    gword[p] = *(const uint32_t*)(Ag +
        ((size_t)(st_t*BB + b)*HH + p)*NN + n0 + st_n4*4);

  auto xustage = [&](int h, int buf){
#pragma unroll
    for (int i = 0; i < 8; ++i){
      const u8* g = Sk + ((size_t)((wid*BB + b)*CC) + (size_t)(h*64 + i*8 + (lane >> 3)))*NN
                       + n0 + (lane & 7)*4;
      gld_lds4(g, (void*)&xu[buf][(wid*64 + i*8)*32]);
    }
  };
  auto loadPA = [&](int p){
#pragma unroll
    for (int s = 0; s < 2; ++s)
#pragma unroll
      for (int ks = 0; ks < 4; ++ks)
        Ap[s*4 + ks] = *(const uint4*)(WF +
            ((size_t)(s*64 + p*8 + ks*2 + hi)*512 + rowA) * 16);
  };
  auto stage2 = [&](int buf, uint32_t g32){
    uint32_t r[8];
#pragma unroll
    for (int c = 0; c < 8; ++c)
      r[c] = *(const uint32_t*)&xu[buf][(st_t*64 + st_kh*8 + c)*32 + st_n4*4];
#pragma unroll
    for (int j = 0; j < 4; ++j){
      const uint32_t gm   = __builtin_amdgcn_perm(g32, g32, (uint32_t)j * 0x01010101u);
      const uint32_t selp = (uint32_t)j | (((uint32_t)j + 4u) << 8);
      uint32_t p01 = __builtin_amdgcn_perm(r[1], r[0], selp);
      uint32_t p23 = __builtin_amdgcn_perm(r[3], r[2], selp);
      uint32_t p45 = __builtin_amdgcn_perm(r[5], r[4], selp);
      uint32_t p67 = __builtin_amdgcn_perm(r[7], r[6], selp);
      uint32_t lo = __builtin_amdgcn_perm(p23, p01, 0x05040100u) & gm;
      uint32_t hi_ = __builtin_amdgcn_perm(p67, p45, 0x05040100u) & gm;
      uint32_t w[4];
#pragma unroll
      for (int p = 0; p < 4; ++p){
        const uint32_t src = (p < 2) ? lo : hi_;
        const uint32_t b0 = (src >> ((p & 1) * 16)) & 0xFFu;
        const uint32_t b1 = (src >> ((p & 1) * 16 + 8)) & 0xFFu;
        w[p] = (b0 ? 0x3C00u : 0u) | (b1 ? 0x3C000000u : 0u);
      }
      frag[st_kh*128 + st_t*32 + st_n4*4 + j] = make_uint4(w[0], w[1], w[2], w[3]);
    }
  };
  auto mstepP = [&](){
#pragma unroll
    for (int ks = 0; ks < 4; ++ks){
      const int kb = ks*2 + hi;
#pragma unroll
      for (int ct = 0; ct < 4; ++ct){
        const int fb = ct*32 + ln31;
        f16x8 bb = ash(frag[kb*128 + fb]);
        acc[ct] = MFMA_F16(ash(Ap[ks]),     bb, acc[ct]);
        acc[ct] = MFMA_F16(ash(Ap[4 + ks]), bb, acc[ct]);
      }
    }
  };

#define PJ_BODY(P, VM) { \
    WAITVM(VM); SBAR(); \
    loadPA(P); \
    stage2((P)%3, gword[P]); \
    if ((P) < 6) xustage((P)+2, ((P)+2)%3); \
    WAITLGKM0; SBAR(); \
    mstepP(); }

  xustage(0, 0); xustage(1, 1);
  PJ_BODY(0,8)  PJ_BODY(1,16) PJ_BODY(2,16) PJ_BODY(3,16)
  PJ_BODY(4,16) PJ_BODY(5,16) PJ_BODY(6,16) PJ_BODY(7,8)
#undef PJ_BODY

  float c1[16], c0[16];
#pragma unroll
  for (int rg = 0; rg < 4; ++rg){
    const int dbase = d0 + wid*32 + rg*8 + hi*4;
    const float4 g4 = *(const float4*)&gamma[dbase];
    const float4 b4 = *(const float4*)&beta[dbase];
    const float4 m4 = *(const float4*)&mean[dbase];
    const float4 v4 = *(const float4*)&var[dbase];
    const float4 s4 = *(const float4*)&bias[dbase];
    const float* gp = (const float*)&g4;
    const float* bp = (const float*)&b4;
    const float* mp = (const float*)&m4;
    const float* vp = (const float*)&v4;
    const float* sp = (const float*)&s4;
#pragma unroll
    for (int j = 0; j < 4; ++j){
      const float inv = gp[j] * (1.0f / sqrtf(vp[j] + 1e-5f));
      c1[rg*4 + j] = inv * (1.0f/64.0f);
      c0[rg*4 + j] = (sp[j] - mp[j])*inv + bp[j];
    }
  }

#pragma unroll
  for (int rg = 0; rg < 4; ++rg)
#pragma unroll
    for (int j = 0; j < 4; ++j){
      const int r = rg*4 + j;
      const int d = d0 + wid*32 + j + rg*8 + hi*4;
      float v = 0.f;
#pragma unroll
      for (int t = 0; t < 4; ++t){
        const float y = fmaf(acc[t][r], c1[r], c0[r]);
        v = 0.5f*(v + y);
        const bool s = (v >= 1.0f);
        if (s) v = 0.f;
        O[((size_t)(t*BB + b)*CC + d)*NN + n0 + ln31] = s ? 1.f : 0.f;
      }
    }
}

// ---------------------------------------------------------------------------
extern "C" void kernel_launch(void* const* d_in, const int* in_sizes, int n_in,
                              void* d_out, int out_size, void* d_ws, size_t ws_size,
                              hipStream_t stream)
{
  const float* q   = (const float*)d_in[0];
  const float* k   = (const float*)d_in[1];
  const float* qw  = (const float*)d_in[2];
  const float* kw  = (const float*)d_in[3];
  const float* pw  = (const float*)d_in[4];
  const float* pb  = (const float*)d_in[5];
  const float* qg  = (const float*)d_in[6];
  const float* qbt = (const float*)d_in[7];
  const float* qm  = (const float*)d_in[8];
  const float* qv  = (const float*)d_in[9];
  const float* kg  = (const float*)d_in[10];
  const float* kbt = (const float*)d_in[11];
  const float* km  = (const float*)d_in[12];
  const float* kv  = (const float*)d_in[13];
  const float* pg  = (const float*)d_in[14];
  const float* pbt = (const float*)d_in[15];
  const float* pm  = (const float*)d_in[16];
  const float* pv  = (const float*)d_in[17];

  u8* WFq = (u8*)d_ws;
  u8* WFk = WFq + WF_BYTES;
  u8* WFp = WFk + WF_BYTES;
  u8* XFq = WFp + WF_BYTES;
  u8* XFk = XFq + XF_BYTES;
  u8* Sk  = XFk + XF_BYTES;
  u8* Aa  = Sk + SZ_SPIKE;
  const size_t need = 3*WF_BYTES + 2*XF_BYTES + SZ_SPIKE + SZ_GATE;
  if (ws_size < need) return;

  k_prep<<<dim3(128, 3), 256, 0, stream>>>(qw, kw, pw, WFq, WFk, WFp);
  k_splitx<<<dim3(4, 16, 64), 256, 0, stream>>>(q, k, XFq, XFk);
  k_qk<<<2048, 256, 0, stream>>>(XFq, XFk, WFq, WFk,
                                 qg, qbt, qm, qv, kg, kbt, km, kv, Sk, Aa);
  k_proj<<<1024, 256, 0, stream>>>(Sk, Aa, WFp, pb, pg, pbt, pm, pv, (float*)d_out);
}

// Round 5
// 163.538 us; speedup vs baseline: 3.8935x; 1.3820x over previous
//
#include <hip/hip_runtime.h>
#include <hip/hip_fp16.h>
#include <stdint.h>

#define TT 4
#define BB 8
#define CC 512
#define NN 1024
#define HH 8

typedef unsigned char u8;
typedef _Float16 f16x8 __attribute__((ext_vector_type(8)));
typedef float f32x16 __attribute__((ext_vector_type(16)));

#define WF_BYTES ((size_t)2*64*512*16)        /* 1 MiB per weight (fp16x2 frags) */
#define SZ_SPIKE ((size_t)TT*BB*CC*NN)        /* 16 MiB */
#define SZ_GATE  ((size_t)TT*BB*HH*NN)        /* 256 KiB */

union U4H { uint4 u; f16x8 v; };
__device__ __forceinline__ f16x8 ash(uint4 u){ U4H x; x.u = u; return x.v; }

#define MFMA_F16(a,b,c) __builtin_amdgcn_mfma_f32_32x32x16_f16((a),(b),(c),0,0,0)

__device__ __forceinline__ void gld_lds16(const void* g, void* l){
  __builtin_amdgcn_global_load_lds((const __attribute__((address_space(1))) void*)g,
                                   (__attribute__((address_space(3))) void*)l, 16, 0, 0);
}
__device__ __forceinline__ void gld_lds4(const void* g, void* l){
  __builtin_amdgcn_global_load_lds((const __attribute__((address_space(1))) void*)g,
                                   (__attribute__((address_space(3))) void*)l, 4, 0, 0);
}

#define WAITVM(N) asm volatile("s_waitcnt vmcnt(" #N ")" ::: "memory")
#define WAITLGKM0 asm volatile("s_waitcnt lgkmcnt(0)" ::: "memory")
#define SBAR() __builtin_amdgcn_s_barrier()
#define VMFENCE() asm volatile("" ::: "memory")   /* pin VMEM issue order (FIFO) */

// fp16x2 split of a scaled fp32: xs = h + m + r, |r| <= 2^-24 |xs|
__device__ __forceinline__ void split16(float xs, uint32_t& h, uint32_t& m){
  __half hh = __float2half(xs);
  float hf = __half2float(hh);
  __half mm = __float2half(xs - hf);
  h = __half_as_ushort(hh);
  m = __half_as_ushort(mm);
}

// ---------------------------------------------------------------------------
// prep: W [512x512] fp32 -> fp16x2 frags (scale 64), layout [s][kh64][row512]x16B
// ---------------------------------------------------------------------------
__global__ __launch_bounds__(256)
void k_prep(const float* __restrict__ W0, const float* __restrict__ W1,
            const float* __restrict__ W2,
            u8* __restrict__ D0, u8* __restrict__ D1, u8* __restrict__ D2)
{
  const int which = blockIdx.y;
  const float* W = (which == 0) ? W0 : (which == 1) ? W1 : W2;
  u8* D = (which == 0) ? D0 : (which == 1) ? D1 : D2;
  const int tg  = blockIdx.x * 256 + threadIdx.x;
  const int row = tg >> 6;
  const int kh  = tg & 63;
  uint32_t Hw[4], Mw[4];
#pragma unroll
  for (int p = 0; p < 4; ++p){
    uint32_t h0, m0, h1, m1;
    split16(W[row * CC + kh * 8 + 2*p    ] * 64.0f, h0, m0);
    split16(W[row * CC + kh * 8 + 2*p + 1] * 64.0f, h1, m1);
    Hw[p] = h0 | (h1 << 16);
    Mw[p] = m0 | (m1 << 16);
  }
  *(uint4*)(D + ((size_t)(0*64 + kh)*512 + row) * 16) = make_uint4(Hw[0],Hw[1],Hw[2],Hw[3]);
  *(uint4*)(D + ((size_t)(1*64 + kh)*512 + row) * 16) = make_uint4(Mw[0],Mw[1],Mw[2],Mw[3]);
}

// ---------------------------------------------------------------------------
// q/k path: stage raw fp32 X -> in-LDS fp16x2 split -> 3-pass GEMM + BN + LIF
//   k-path -> u8 spikes Sk;  q-path -> head-OR gate Aa (register-only reduce)
// 4 waves x (64d x 128col=4t*32n); block 256d x 128col; K=32 phases x16
// grid 1024: lg = (((path*8+b)*32+n0i)*2 + d0t), XCD-chunked swizzle
// ---------------------------------------------------------------------------
__global__ __launch_bounds__(256, 2)
void k_qk(const float* __restrict__ Q, const float* __restrict__ K,
          const u8* __restrict__ WFq, const u8* __restrict__ WFk,
          const float* __restrict__ qg, const float* __restrict__ qb,
          const float* __restrict__ qm, const float* __restrict__ qv,
          const float* __restrict__ kg, const float* __restrict__ kb,
          const float* __restrict__ km, const float* __restrict__ kv,
          u8* __restrict__ Sk, u8* __restrict__ Aa)
{
  __shared__ float xf32[3][4096];               // ring-3: [t4][k32][n32] fp32
  __shared__ uint4 frag[1024];                  // [kb8(h0-3,m4-7)][col128]

  const int hw = blockIdx.x;
  const int lg = (hw & 7) * 128 + (hw >> 3);
  const int d0t  = lg & 1;
  const int n0i  = (lg >> 1) & 31;
  const int b    = (lg >> 6) & 7;
  const int path = (lg >> 9) & 1;
  const int n0 = n0i << 5, d0 = d0t << 8;
  const float* X = path ? K : Q;
  const u8* WF = path ? WFk : WFq;

  const int tid = threadIdx.x, lane = tid & 63, wid = tid >> 6;
  const int hi = lane >> 5, ln31 = lane & 31;

  f32x16 acc[4][2];
#pragma unroll
  for (int t = 0; t < 4; ++t)
#pragma unroll
    for (int rt = 0; rt < 2; ++rt)
#pragma unroll
      for (int r = 0; r < 16; ++r) acc[t][rt][r] = 0.0f;

  uint4 A0[8], A1[8];

  // wave wid stages t=wid quarter: 4 x 1KB DMA, linear LDS dest
  auto stageX = [&](int h, int buf){
    const float* xb = X + ((size_t)(wid*BB + b)*CC + h*32)*NN + n0;
#pragma unroll
    for (int i = 0; i < 4; ++i){
      gld_lds16(xb + (size_t)(i*8 + (lane >> 3))*NN + ((lane & 7) << 2),
                (void*)&xf32[buf][(wid*32 + i*8)*32]);
    }
  };
  auto loadA = [&](uint4* A, int h){
#pragma unroll
    for (int s = 0; s < 2; ++s)
#pragma unroll
      for (int ks = 0; ks < 2; ++ks)
#pragma unroll
        for (int rt = 0; rt < 2; ++rt)
          A[s*4 + ks*2 + rt] = *(const uint4*)(WF +
              ((size_t)(s*64 + h*4 + ks*2 + hi)*512
               + d0 + wid*64 + rt*32 + ln31) * 16);
  };
  // split fp32 -> h/m fp16 frags; thread: col c, 16 consecutive k
  auto dosplit = [&](int sb){
    const int c = tid & 127;
    const int t = c >> 5, n = c & 31;
    const int k0 = (tid >> 7) << 4;             // 0 or 16
    const float* xs = &xf32[sb][(t*32 + k0)*32 + n];
    uint32_t hw_[8], mw_[8];
#pragma unroll
    for (int p = 0; p < 8; ++p){
      uint32_t ha, ma, hb2, mb2;
      split16(xs[(2*p  )*32] * 512.0f, ha, ma);
      split16(xs[(2*p+1)*32] * 512.0f, hb2, mb2);
      hw_[p] = ha | (hb2 << 16);
      mw_[p] = ma | (mb2 << 16);
    }
    const int kb0 = k0 >> 3;                    // 0 or 2
    frag[(kb0    )*128 + c] = make_uint4(hw_[0],hw_[1],hw_[2],hw_[3]);
    frag[(kb0 + 1)*128 + c] = make_uint4(hw_[4],hw_[5],hw_[6],hw_[7]);
    frag[(4 + kb0    )*128 + c] = make_uint4(mw_[0],mw_[1],mw_[2],mw_[3]);
    frag[(4 + kb0 + 1)*128 + c] = make_uint4(mw_[4],mw_[5],mw_[6],mw_[7]);
  };
  auto mstep = [&](const uint4* A){
#pragma unroll
    for (int ks = 0; ks < 2; ++ks){
      const int kbi = ks*2 + hi;
#pragma unroll
      for (int ct = 0; ct < 4; ++ct){
        const int fb = ct*32 + ln31;
        f16x8 bh = ash(frag[kbi*128 + fb]);
        f16x8 bm = ash(frag[(4 + kbi)*128 + fb]);
#pragma unroll
        for (int rt = 0; rt < 2; ++rt){
          acc[ct][rt] = MFMA_F16(ash(A[0*4 + ks*2 + rt]), bh, acc[ct][rt]); // Wh*Xh
          acc[ct][rt] = MFMA_F16(ash(A[1*4 + ks*2 + rt]), bh, acc[ct][rt]); // Wm*Xh
          acc[ct][rt] = MFMA_F16(ash(A[0*4 + ks*2 + rt]), bm, acc[ct][rt]); // Wh*Xm
        }
      }
    }
  };

  // phase: WAITVM; SBAR; loadA(H+1); stageX(H+2); split(H); LGKM+SBAR; mstep(H)
#define QK_PH(H, VM) { \
    WAITVM(VM); SBAR(); \
    if ((H) < 15) { loadA(((H)&1) ? A0 : A1, (H)+1); VMFENCE(); } \
    if ((H) < 14) { stageX((H)+2, ((H)+2)%3); VMFENCE(); } \
    dosplit((H)%3); \
    WAITLGKM0; SBAR(); \
    mstep(((H)&1) ? A1 : A0); }

  stageX(0, 0); VMFENCE(); stageX(1, 1); VMFENCE(); loadA(A0, 0);
  QK_PH(0,12)  QK_PH(1,12)  QK_PH(2,12)  QK_PH(3,12)
  QK_PH(4,12)  QK_PH(5,12)  QK_PH(6,12)  QK_PH(7,12)
  QK_PH(8,12)  QK_PH(9,12)  QK_PH(10,12) QK_PH(11,12)
  QK_PH(12,12) QK_PH(13,12) QK_PH(14,12) QK_PH(15,8)
#undef QK_PH

  const float* gamma = path ? kg : qg;
  const float* beta  = path ? kb : qb;
  const float* mean  = path ? km : qm;
  const float* var   = path ? kv : qv;

  uint32_t orb = 0;
#pragma unroll
  for (int rt = 0; rt < 2; ++rt)
#pragma unroll
    for (int rg = 0; rg < 4; ++rg){
      const int dbase = d0 + wid*64 + rt*32 + rg*8 + hi*4;
      const float4 g4 = *(const float4*)&gamma[dbase];
      const float4 b4 = *(const float4*)&beta[dbase];
      const float4 m4 = *(const float4*)&mean[dbase];
      const float4 v4 = *(const float4*)&var[dbase];
      const float* gp = (const float*)&g4;
      const float* bp = (const float*)&b4;
      const float* mp = (const float*)&m4;
      const float* vp = (const float*)&v4;
#pragma unroll
      for (int j = 0; j < 4; ++j){
        const float inv = gp[j] * (1.0f / sqrtf(vp[j] + 1e-5f));
        const float c1 = inv * (1.0f/32768.0f);
        const float c0 = bp[j] - mp[j]*inv;
        const int r = rg*4 + j;
        float v = 0.f;
#pragma unroll
        for (int t = 0; t < 4; ++t){
          const float y = fmaf(acc[t][rt][r], c1, c0);
          v = 0.5f*(v + y);
          const bool s = (v >= 1.0f);
          if (s) v = 0.f;
          if (path == 1)
            Sk[((size_t)(t*BB + b)*CC + dbase + j)*NN + n0 + ln31] = (u8)s;
          else
            orb |= ((uint32_t)s) << t;
        }
      }
    }

  if (path == 0){
    // wave wid == head (64 d per wave): OR across lane pair (l, l^32)
    orb |= __shfl_xor(orb, 32);
    if (hi == 0){
      const int h = d0t*4 + wid;
#pragma unroll
      for (int t = 0; t < 4; ++t)
        Aa[((size_t)(t*BB + b)*HH + h)*NN + n0 + ln31] = (u8)((orb >> t) & 1);
    }
  }
}

// ---------------------------------------------------------------------------
// proj: x = (attn & k_s) exact in fp16; W fp16x2 -> 2 passes; +bias,BN,LIF
// 4 waves x (64d x 128col); block 256d x 128col; K=64 phases x8
// grid 512: lg = ((b*32+n0i)*2 + d0t), XCD-chunked swizzle
// ---------------------------------------------------------------------------
__global__ __launch_bounds__(256, 2)
void k_proj(const u8* __restrict__ Sk, const u8* __restrict__ Ag,
            const u8* __restrict__ WF, const float* __restrict__ bias,
            const float* __restrict__ gamma, const float* __restrict__ beta,
            const float* __restrict__ mean, const float* __restrict__ var,
            float* __restrict__ O)
{
  __shared__ u8   xu[3][8192];                  // ring-3: [t4][k64][n32] u8
  __shared__ uint4 frag[1024];                  // [kb8][col128]

  const int hw = blockIdx.x;
  const int lg = (hw & 7) * 64 + (hw >> 3);
  const int d0t = lg & 1;
  const int n0i = (lg >> 1) & 31;
  const int b   = (lg >> 6) & 7;
  const int n0 = n0i << 5, d0 = d0t << 8;

  const int tid = threadIdx.x, lane = tid & 63, wid = tid >> 6;
  const int hi = lane >> 5, ln31 = lane & 31;

  const int st_kh = tid >> 5, st_t = (tid >> 3) & 3, st_n4 = tid & 7;

  f32x16 acc[4][2];
#pragma unroll
  for (int t = 0; t < 4; ++t)
#pragma unroll
    for (int rt = 0; rt < 2; ++rt)
#pragma unroll
      for (int r = 0; r < 16; ++r) acc[t][rt][r] = 0.0f;

  uint4 Ap[16];
  uint32_t gword[8];
#pragma unroll
  for (int p = 0; p < 8; ++p)
    gword[p] = *(const uint32_t*)(Ag +
        ((size_t)(st_t*BB + b)*HH + p)*NN + n0 + st_n4*4);

  auto xustage = [&](int h, int buf){
#pragma unroll
    for (int i = 0; i < 8; ++i){
      const u8* g = Sk + ((size_t)((wid*BB + b)*CC) + (size_t)(h*64 + i*8 + (lane >> 3)))*NN
                       + n0 + (lane & 7)*4;
      gld_lds4(g, (void*)&xu[buf][(wid*64 + i*8)*32]);
    }
  };
  auto loadPA = [&](int p){
#pragma unroll
    for (int s = 0; s < 2; ++s)
#pragma unroll
      for (int ks = 0; ks < 4; ++ks)
#pragma unroll
        for (int rt = 0; rt < 2; ++rt)
          Ap[(s*4 + ks)*2 + rt] = *(const uint4*)(WF +
              ((size_t)(s*64 + p*8 + ks*2 + hi)*512
               + d0 + wid*64 + rt*32 + ln31) * 16);
  };
  auto stage2 = [&](int buf, uint32_t g32){
    uint32_t r[8];
#pragma unroll
    for (int c = 0; c < 8; ++c)
      r[c] = *(const uint32_t*)&xu[buf][(st_t*64 + st_kh*8 + c)*32 + st_n4*4];
#pragma unroll
    for (int j = 0; j < 4; ++j){
      const uint32_t gm   = __builtin_amdgcn_perm(g32, g32, (uint32_t)j * 0x01010101u);
      const uint32_t selp = (uint32_t)j | (((uint32_t)j + 4u) << 8);
      uint32_t p01 = __builtin_amdgcn_perm(r[1], r[0], selp);
      uint32_t p23 = __builtin_amdgcn_perm(r[3], r[2], selp);
      uint32_t p45 = __builtin_amdgcn_perm(r[5], r[4], selp);
      uint32_t p67 = __builtin_amdgcn_perm(r[7], r[6], selp);
      uint32_t lo  = __builtin_amdgcn_perm(p23, p01, 0x05040100u) & gm;
      uint32_t hi_ = __builtin_amdgcn_perm(p67, p45, 0x05040100u) & gm;
      uint32_t w[4];
#pragma unroll
      for (int p = 0; p < 4; ++p){
        const uint32_t src = (p < 2) ? lo : hi_;
        const uint32_t b0 = (src >> ((p & 1) * 16)) & 0xFFu;
        const uint32_t b1 = (src >> ((p & 1) * 16 + 8)) & 0xFFu;
        w[p] = (b0 ? 0x3C00u : 0u) | (b1 ? 0x3C000000u : 0u);
      }
      frag[st_kh*128 + st_t*32 + st_n4*4 + j] = make_uint4(w[0], w[1], w[2], w[3]);
    }
  };
  auto mstepP = [&](){
#pragma unroll
    for (int ks = 0; ks < 4; ++ks){
      const int kbi = ks*2 + hi;
#pragma unroll
      for (int ct = 0; ct < 4; ++ct){
        const int fb = ct*32 + ln31;
        f16x8 bb = ash(frag[kbi*128 + fb]);
#pragma unroll
        for (int rt = 0; rt < 2; ++rt){
          acc[ct][rt] = MFMA_F16(ash(Ap[(0*4 + ks)*2 + rt]), bb, acc[ct][rt]);
          acc[ct][rt] = MFMA_F16(ash(Ap[(1*4 + ks)*2 + rt]), bb, acc[ct][rt]);
        }
      }
    }
  };

#define PJ_PH(P, VM) { \
    WAITVM(VM); SBAR(); \
    loadPA(P); VMFENCE(); \
    if ((P) < 6) { xustage((P)+2, ((P)+2)%3); VMFENCE(); } \
    stage2((P)%3, gword[P]); \
    WAITLGKM0; SBAR(); \
    mstepP(); }

  xustage(0, 0); VMFENCE(); xustage(1, 1); VMFENCE();
  PJ_PH(0,8) PJ_PH(1,8) PJ_PH(2,8) PJ_PH(3,8)
  PJ_PH(4,8) PJ_PH(5,8) PJ_PH(6,8) PJ_PH(7,0)
#undef PJ_PH

#pragma unroll
  for (int rt = 0; rt < 2; ++rt)
#pragma unroll
    for (int rg = 0; rg < 4; ++rg){
      const int dbase = d0 + wid*64 + rt*32 + rg*8 + hi*4;
      const float4 g4 = *(const float4*)&gamma[dbase];
      const float4 b4 = *(const float4*)&beta[dbase];
      const float4 m4 = *(const float4*)&mean[dbase];
      const float4 v4 = *(const float4*)&var[dbase];
      const float4 s4 = *(const float4*)&bias[dbase];
      const float* gp = (const float*)&g4;
      const float* bp = (const float*)&b4;
      const float* mp = (const float*)&m4;
      const float* vp = (const float*)&v4;
      const float* sp = (const float*)&s4;
#pragma unroll
      for (int j = 0; j < 4; ++j){
        const float inv = gp[j] * (1.0f / sqrtf(vp[j] + 1e-5f));
        const float c1 = inv * (1.0f/64.0f);
        const float c0 = (sp[j] - mp[j])*inv + bp[j];
        const int r = rg*4 + j;
        float v = 0.f;
#pragma unroll
        for (int t = 0; t < 4; ++t){
          const float y = fmaf(acc[t][rt][r], c1, c0);
          v = 0.5f*(v + y);
          const bool s = (v >= 1.0f);
          if (s) v = 0.f;
          O[((size_t)(t*BB + b)*CC + dbase + j)*NN + n0 + ln31] = s ? 1.f : 0.f;
        }
      }
    }
}

// ---------------------------------------------------------------------------
extern "C" void kernel_launch(void* const* d_in, const int* in_sizes, int n_in,
                              void* d_out, int out_size, void* d_ws, size_t ws_size,
                              hipStream_t stream)
{
  const float* q   = (const float*)d_in[0];
  const float* k   = (const float*)d_in[1];
  const float* qw  = (const float*)d_in[2];
  const float* kw  = (const float*)d_in[3];
  const float* pw  = (const float*)d_in[4];
  const float* pb  = (const float*)d_in[5];
  const float* qg  = (const float*)d_in[6];
  const float* qbt = (const float*)d_in[7];
  const float* qm  = (const float*)d_in[8];
  const float* qv  = (const float*)d_in[9];
  const float* kg  = (const float*)d_in[10];
  const float* kbt = (const float*)d_in[11];
  const float* km  = (const float*)d_in[12];
  const float* kv  = (const float*)d_in[13];
  const float* pg  = (const float*)d_in[14];
  const float* pbt = (const float*)d_in[15];
  const float* pm  = (const float*)d_in[16];
  const float* pv  = (const float*)d_in[17];

  u8* WFq = (u8*)d_ws;
  u8* WFk = WFq + WF_BYTES;
  u8* WFp = WFk + WF_BYTES;
  u8* Sk  = WFp + WF_BYTES;
  u8* Aa  = Sk + SZ_SPIKE;
  const size_t need = 3*WF_BYTES + SZ_SPIKE + SZ_GATE;
  if (ws_size < need) return;

  k_prep<<<dim3(128, 3), 256, 0, stream>>>(qw, kw, pw, WFq, WFk, WFp);
  k_qk<<<1024, 256, 0, stream>>>(q, k, WFq, WFk,
                                 qg, qbt, qm, qv, kg, kbt, km, kv, Sk, Aa);
  k_proj<<<512, 256, 0, stream>>>(Sk, Aa, WFp, pb, pg, pbt, pm, pv, (float*)d_out);
}